// Round 5
// baseline (782.840 us; speedup 1.0000x reference)
//
#include <hip/hip_runtime.h>
#include <math.h>

#define TT 2048

typedef __attribute__((ext_vector_type(8))) short bfrag;   // 8 bf16 in 4 VGPRs
typedef __attribute__((ext_vector_type(4))) float facc;    // 4 fp32 acc

#define NEG_BIG (-1.0e30f)

typedef __attribute__((address_space(1))) const void gas_void;
typedef __attribute__((address_space(3))) void las_void;

__device__ __forceinline__ void gl_lds16(const void* g, void* l) {
    __builtin_amdgcn_global_load_lds((gas_void*)g, (las_void*)l, 16, 0, 0);
}

__device__ __forceinline__ unsigned short f2b(float f) {
    union { float f; unsigned int i; } v; v.f = f;
    unsigned int b = v.i;
    return (unsigned short)((b + 0x7FFFu + ((b >> 16) & 1u)) >> 16);  // RNE
}
__device__ __forceinline__ void cvt8_f32(const float* __restrict__ p, unsigned short* d) {
    float4 lo = *(const float4*)p, hi = *(const float4*)(p + 4);
    d[0] = f2b(lo.x); d[1] = f2b(lo.y); d[2] = f2b(lo.z); d[3] = f2b(lo.w);
    d[4] = f2b(hi.x); d[5] = f2b(hi.y); d[6] = f2b(hi.z); d[7] = f2b(hi.w);
}

#define SBAR() asm volatile("s_barrier" ::: "memory")
#define LGKM0() do { asm volatile("s_waitcnt lgkmcnt(0)" ::: "memory"); \
                     __builtin_amdgcn_sched_barrier(0); } while (0)

// ---------------------------------------------------------------------------
// fp32 -> bf16 flat convert (n8 = count of 8-element chunks)
// ---------------------------------------------------------------------------
__global__ __launch_bounds__(256) void k_cvt(const float* __restrict__ in,
                                             unsigned short* __restrict__ out, int n8) {
    int c = blockIdx.x * 256 + threadIdx.x;
    if (c < n8) {
        unsigned short t[8];
        cvt8_f32(in + (size_t)c * 8, t);
        *(uint4*)(out + (size_t)c * 8) = *(const uint4*)t;
    }
}

// ---------------------------------------------------------------------------
// Weight transpose+convert: W (2048 x N fp32, row-major) -> WT (N x 2048 bf16)
// ---------------------------------------------------------------------------
__global__ __launch_bounds__(256) void k_wt(const float* __restrict__ W,
                                            unsigned short* __restrict__ WT, int N) {
    __shared__ alignas(16) unsigned short tile[64][72];
    int r0 = blockIdx.y * 64, c0 = blockIdx.x * 64;
    int tid = threadIdx.x;
    for (int i = 0; i < 2; ++i) {
        int c = tid + i * 256;
        int row = c >> 3, c8 = (c & 7) * 8;
        unsigned short t[8];
        cvt8_f32(W + (size_t)(r0 + row) * N + c0 + c8, t);
        *(uint4*)&tile[row][c8] = *(const uint4*)t;
    }
    __syncthreads();
    for (int i = 0; i < 2; ++i) {
        int c = tid + i * 256;
        int col = c >> 3, r8 = (c & 7) * 8;
        unsigned short t[8];
        for (int j = 0; j < 8; ++j) t[j] = tile[r8 + j][col];
        *(uint4*)(WT + (size_t)(c0 + col) * 2048 + r0 + r8) = *(const uint4*)t;
    }
}

// ---------------------------------------------------------------------------
// V transpose: QKV (8192 x 3072 bf16, V = cols 2560..3071) -> VbT (512 x 8192)
// ---------------------------------------------------------------------------
__global__ __launch_bounds__(256) void k_vt(const unsigned short* __restrict__ QKV,
                                            unsigned short* __restrict__ VbT) {
    __shared__ alignas(16) unsigned short tile[64][72];
    int r0 = blockIdx.y * 64, c0 = blockIdx.x * 64;
    int tid = threadIdx.x;
    for (int i = 0; i < 2; ++i) {
        int c = tid + i * 256;
        int row = c >> 3, c8 = (c & 7) * 8;
        *(uint4*)&tile[row][c8] =
            *(const uint4*)(QKV + (size_t)(r0 + row) * 3072 + 2560 + c0 + c8);
    }
    __syncthreads();
    for (int i = 0; i < 2; ++i) {
        int c = tid + i * 256;
        int col = c >> 3, r8 = (c & 7) * 8;
        unsigned short t[8];
        for (int j = 0; j < 8; ++j) t[j] = tile[r8 + j][col];
        *(uint4*)(VbT + (size_t)(c0 + col) * 8192 + r0 + r8) = *(const uint4*)t;
    }
}

// ---------------------------------------------------------------------------
// 256x256 8-phase GEMM (m201 template), SPILL-FIXED: all loops unrolled so
// every acc[] index is compile-time constant (round-2 failure was the
// non-unrolled epilogue rg-loop runtime-indexing acc -> whole acc array in
// scratch: VGPR=116, WRITE 5x, MfmaUtil 13%).
// BK=64, 8 waves (2M x 4N), per-wave 128x64 output, 128 KiB LDS dbuf.
// Counted vmcnt(4) at tile boundary; staging order per wave:
//   (t+1).A0 [ph0], (t+1).A1 [ph1], (t+2).B0 [ph2], (t+2).B1 [ph3]
// Invariant at start of t: exactly B(t+1)'s 4 loads in flight.
// ---------------------------------------------------------------------------
__global__ __launch_bounds__(512, 2) void k_gemm256(const unsigned short* __restrict__ A,
                                                    const unsigned short* __restrict__ Bt,
                                                    void* __restrict__ Cmat,
                                                    int M, int N, int K, int outF) {
    __shared__ union SM {
        struct { unsigned short A[2][256][64]; unsigned short B[2][256][64]; } s; // 128 KiB
        float          ctf[32][260];
        unsigned short ct [32][264];
    } sm;

    int tid = threadIdx.x;
    int w = tid >> 6, lane = tid & 63, quad = lane >> 4, l15 = lane & 15;
    int wr = w >> 2, wc = w & 3;          // 2M x 4N wave grid
    int wrb = wr * 128, wcb = wc * 64;

    // bijective XCD swizzle (grids here are %8 == 0)
    int nwg = gridDim.x * gridDim.y;
    int bid = blockIdx.y * gridDim.x + blockIdx.x;
    int cpx = nwg >> 3;
    int sid = (bid & 7) * cpx + (bid >> 3);
    int bx = sid % gridDim.x, by = sid / gridDim.x;
    int m0 = by * 256, n0 = bx * 256;

    // staging: lane writes LDS row (base + lane>>3), slot lane&7 (linear);
    // source chunk = (lane&7) ^ (lane>>3) so LDS[row][slot] = global chunk
    // slot ^ (row&7).
    int srow = w * 8 + (lane >> 3);
    int sch  = (lane & 7) ^ (lane >> 3);

    auto stageA = [&](int bb, int h, int tt) {
        const unsigned short* src = A + (size_t)(m0 + h * 128 + srow) * K + tt * 64 + sch * 8;
        gl_lds16(src,                   &sm.s.A[bb][h * 128 + w * 8][0]);
        gl_lds16(src + (size_t)64 * K,  &sm.s.A[bb][h * 128 + 64 + w * 8][0]);
    };
    auto stageB = [&](int bb, int h, int tt) {
        const unsigned short* src = Bt + (size_t)(n0 + h * 128 + srow) * K + tt * 64 + sch * 8;
        gl_lds16(src,                   &sm.s.B[bb][h * 128 + w * 8][0]);
        gl_lds16(src + (size_t)64 * K,  &sm.s.B[bb][h * 128 + 64 + w * 8][0]);
    };

    // reader: physical slot = (kk*4+quad) ^ (row&7); row&7 == l15&7.
#define AFRAG(bb, r, kk) (*(const bfrag*)&sm.s.A[bb][r][((((kk) * 4 + quad) ^ ((r) & 7)) * 8)])
#define BFRAG(bb, r, kk) (*(const bfrag*)&sm.s.B[bb][r][((((kk) * 4 + quad) ^ ((r) & 7)) * 8)])

    facc acc[8][4];
#pragma unroll
    for (int m = 0; m < 8; ++m)
#pragma unroll
        for (int n = 0; n < 4; ++n)
#pragma unroll
            for (int r = 0; r < 4; ++r) acc[m][n][r] = 0.f;

    int NT = K >> 6;

    // prologue: tile0 fully + tile1's B halves; vmcnt(4) leaves t1.B in flight
    stageA(0, 0, 0); stageA(0, 1, 0); stageB(0, 0, 0); stageB(0, 1, 0);
    if (NT > 1) {
        stageB(1, 0, 1); stageB(1, 1, 1);
        asm volatile("s_waitcnt vmcnt(4)" ::: "memory");
    } else {
        asm volatile("s_waitcnt vmcnt(0)" ::: "memory");
    }
    SBAR();

    bfrag aA[4][2], bLo[2][2], bHi[2][2];

    for (int t = 0; t < NT; ++t) {
        int buf = t & 1;
        // ---- ph0: (m-low, n-low); reads 8A + 4B; stage (t+1).A0
#pragma unroll
        for (int m = 0; m < 4; ++m) {
            aA[m][0] = AFRAG(buf, wrb + m * 16 + l15, 0);
            aA[m][1] = AFRAG(buf, wrb + m * 16 + l15, 1);
        }
#pragma unroll
        for (int n = 0; n < 2; ++n) {
            bLo[n][0] = BFRAG(buf, wcb + n * 16 + l15, 0);
            bLo[n][1] = BFRAG(buf, wcb + n * 16 + l15, 1);
        }
        if (t + 1 < NT) stageA(buf ^ 1, 0, t + 1);
        SBAR(); LGKM0();
        __builtin_amdgcn_s_setprio(1);
#pragma unroll
        for (int m = 0; m < 4; ++m)
#pragma unroll
            for (int n = 0; n < 2; ++n)
#pragma unroll
                for (int kk = 0; kk < 2; ++kk)
                    acc[m][n] = __builtin_amdgcn_mfma_f32_16x16x32_bf16(aA[m][kk], bLo[n][kk], acc[m][n], 0, 0, 0);
        __builtin_amdgcn_s_setprio(0);
        SBAR();

        // ---- ph1: (m-low, n-high); reads 4B; stage (t+1).A1
#pragma unroll
        for (int n = 0; n < 2; ++n) {
            bHi[n][0] = BFRAG(buf, wcb + 32 + n * 16 + l15, 0);
            bHi[n][1] = BFRAG(buf, wcb + 32 + n * 16 + l15, 1);
        }
        if (t + 1 < NT) stageA(buf ^ 1, 1, t + 1);
        SBAR(); LGKM0();
        __builtin_amdgcn_s_setprio(1);
#pragma unroll
        for (int m = 0; m < 4; ++m)
#pragma unroll
            for (int n = 0; n < 2; ++n)
#pragma unroll
                for (int kk = 0; kk < 2; ++kk)
                    acc[m][2 + n] = __builtin_amdgcn_mfma_f32_16x16x32_bf16(aA[m][kk], bHi[n][kk], acc[m][2 + n], 0, 0, 0);
        __builtin_amdgcn_s_setprio(0);
        SBAR();

        // ---- ph2: (m-high, n-high); reads 8A; stage (t+2).B0 (B free after ph1)
#pragma unroll
        for (int m = 0; m < 4; ++m) {
            aA[m][0] = AFRAG(buf, wrb + 64 + m * 16 + l15, 0);
            aA[m][1] = AFRAG(buf, wrb + 64 + m * 16 + l15, 1);
        }
        if (t + 2 < NT) stageB(buf, 0, t + 2);
        SBAR(); LGKM0();
        __builtin_amdgcn_s_setprio(1);
#pragma unroll
        for (int m = 0; m < 4; ++m)
#pragma unroll
            for (int n = 0; n < 2; ++n)
#pragma unroll
                for (int kk = 0; kk < 2; ++kk)
                    acc[4 + m][2 + n] = __builtin_amdgcn_mfma_f32_16x16x32_bf16(aA[m][kk], bHi[n][kk], acc[4 + m][2 + n], 0, 0, 0);
        __builtin_amdgcn_s_setprio(0);
        SBAR();

        // ---- ph3: (m-high, n-low); no LDS reads; stage (t+2).B1; boundary wait
        if (t + 2 < NT) stageB(buf, 1, t + 2);
        SBAR();
        __builtin_amdgcn_s_setprio(1);
#pragma unroll
        for (int m = 0; m < 4; ++m)
#pragma unroll
            for (int n = 0; n < 2; ++n)
#pragma unroll
                for (int kk = 0; kk < 2; ++kk)
                    acc[4 + m][n] = __builtin_amdgcn_mfma_f32_16x16x32_bf16(aA[m][kk], bLo[n][kk], acc[4 + m][n], 0, 0, 0);
        __builtin_amdgcn_s_setprio(0);
        if (t < NT - 1) {
            if (t + 2 < NT) asm volatile("s_waitcnt vmcnt(4)" ::: "memory");
            else            asm volatile("s_waitcnt vmcnt(0)" ::: "memory");
        }
        SBAR();
    }
#undef AFRAG
#undef BFRAG

    // epilogue: 8 rounds of 32 rows x 256 cols via LDS, coalesced stores.
    // FULLY UNROLLED so acc indices stay static (rule #20 / round-2 fix).
    __syncthreads();
#pragma unroll
    for (int rg = 0; rg < 8; ++rg) {
        __syncthreads();
        if ((w >> 2) == (rg >> 2)) {
            const int mA = (rg & 3) * 2;
#pragma unroll
            for (int mo = 0; mo < 2; ++mo)
#pragma unroll
                for (int n = 0; n < 4; ++n)
#pragma unroll
                    for (int r = 0; r < 4; ++r) {
                        int lr = mo * 16 + quad * 4 + r;
                        int lc = wc * 64 + n * 16 + l15;
                        if (outF) sm.ctf[lr][lc] = acc[mA + mo][n][r];
                        else      sm.ct [lr][lc] = f2b(acc[mA + mo][n][r]);
                    }
        }
        __syncthreads();
        if (outF) {
#pragma unroll
            for (int i = 0; i < 4; ++i) {
                int cc = tid + i * 512;
                int lr = cc >> 6, c4 = (cc & 63) * 4;
                int grow = m0 + rg * 32 + lr;
                *(float4*)((float*)Cmat + (size_t)grow * N + n0 + c4) =
                    *(const float4*)&sm.ctf[lr][c4];
            }
        } else {
#pragma unroll
            for (int i = 0; i < 2; ++i) {
                int cc = tid + i * 512;
                int lr = cc >> 5, c8 = (cc & 31) * 8;
                int grow = m0 + rg * 32 + lr;
                *(uint4*)((unsigned short*)Cmat + (size_t)grow * N + n0 + c8) =
                    *(const uint4*)&sm.ct[lr][c8];
            }
        }
    }
}

// ---------------------------------------------------------------------------
// m97-style GEMM, BK=64 (round-4 A/B winner: +24% vs BK=32).
// C (MxN) = A (MxK bf16) @ Bt^T. 128x128 tile, global_load_lds width=16,
// XOR chunk swizzle; coalesced LDS-staged epilogue; outF=1 -> fp32.
// ---------------------------------------------------------------------------
template <int BK>
__global__ __launch_bounds__(256) void k_gemm_bt(const unsigned short* __restrict__ A,
                                                 const unsigned short* __restrict__ Bt,
                                                 void* __restrict__ Cmat,
                                                 int M, int N, int K, int outF) {
    __shared__ union SM {
        struct { unsigned short A[128][BK]; unsigned short B[128][BK]; } s;
        unsigned short ct[32][136];
        float          ctf[32][136];
    } sm;
    int tid = threadIdx.x;
    int w = tid >> 6, lane = tid & 63, quad = lane >> 4, l15 = lane & 15;
    int m0 = blockIdx.y * 128, n0 = blockIdx.x * 128;
    int wm = (w >> 1) * 64, wn = (w & 1) * 64;

    facc acc[4][4];
    for (int mi = 0; mi < 4; ++mi)
        for (int ni = 0; ni < 4; ++ni)
            for (int r = 0; r < 4; ++r) acc[mi][ni][r] = 0.f;

    if constexpr (BK == 32) {
        int srow   = lane >> 2;
        int schunk = (lane & 3) ^ ((lane >> 3) & 3);
        int rslot  = (quad ^ ((l15 >> 1) & 3)) * 8;

        for (int k0 = 0; k0 < K; k0 += 32) {
            for (int j = 0; j < 2; ++j) {
                int row = w * 32 + j * 16 + srow;
                gl_lds16(A  + (size_t)(m0 + row) * K + k0 + schunk * 8, &sm.s.A[w * 32 + j * 16][0]);
                gl_lds16(Bt + (size_t)(n0 + row) * K + k0 + schunk * 8, &sm.s.B[w * 32 + j * 16][0]);
            }
            __syncthreads();
            bfrag af[4], bf[4];
            for (int mi = 0; mi < 4; ++mi) af[mi] = *(const bfrag*)&sm.s.A[wm + mi * 16 + l15][rslot];
            for (int ni = 0; ni < 4; ++ni) bf[ni] = *(const bfrag*)&sm.s.B[wn + ni * 16 + l15][rslot];
            for (int mi = 0; mi < 4; ++mi)
                for (int ni = 0; ni < 4; ++ni)
                    acc[mi][ni] = __builtin_amdgcn_mfma_f32_16x16x32_bf16(af[mi], bf[ni], acc[mi][ni], 0, 0, 0);
            __syncthreads();
        }
    } else {
        int srow   = lane >> 3;                       // 0..7
        int schunk = (lane & 7) ^ (lane >> 3);

        for (int k0 = 0; k0 < K; k0 += 64) {
            for (int i = 0; i < 4; ++i) {
                int row = w * 32 + i * 8;
                gl_lds16(A  + (size_t)(m0 + row + srow) * K + k0 + schunk * 8, &sm.s.A[row][0]);
                gl_lds16(Bt + (size_t)(n0 + row + srow) * K + k0 + schunk * 8, &sm.s.B[row][0]);
            }
            __syncthreads();
            bfrag af[4][2], bf[4][2];
            for (int mi = 0; mi < 4; ++mi)
                for (int kc = 0; kc < 2; ++kc)
                    af[mi][kc] = *(const bfrag*)&sm.s.A[wm + mi * 16 + l15][((kc * 4 + quad) ^ (l15 & 7)) * 8];
            for (int ni = 0; ni < 4; ++ni)
                for (int kc = 0; kc < 2; ++kc)
                    bf[ni][kc] = *(const bfrag*)&sm.s.B[wn + ni * 16 + l15][((kc * 4 + quad) ^ (l15 & 7)) * 8];
            for (int kc = 0; kc < 2; ++kc)
                for (int mi = 0; mi < 4; ++mi)
                    for (int ni = 0; ni < 4; ++ni)
                        acc[mi][ni] = __builtin_amdgcn_mfma_f32_16x16x32_bf16(af[mi][kc], bf[ni][kc], acc[mi][ni], 0, 0, 0);
            __syncthreads();
        }
    }

    for (int t = 0; t < 4; ++t) {
        __syncthreads();
        for (int ni = 0; ni < 4; ++ni)
            for (int r = 0; r < 4; ++r) {
                int lr = (w >> 1) * 16 + quad * 4 + r;
                int lc = wn + ni * 16 + l15;
                if (outF) sm.ctf[lr][lc] = acc[t][ni][r];
                else      sm.ct [lr][lc] = f2b(acc[t][ni][r]);
            }
        __syncthreads();
        if (outF) {
            for (int i = 0; i < 4; ++i) {
                int cc = tid + i * 256;
                int lr = cc >> 5, c4 = (cc & 31) * 4;
                int grow = m0 + (lr >> 4) * 64 + t * 16 + (lr & 15);
                *(float4*)((float*)Cmat + (size_t)grow * N + n0 + c4) =
                    *(const float4*)&sm.ctf[lr][c4];
            }
        } else {
            for (int i = 0; i < 2; ++i) {
                int cc = tid + i * 256;
                int lr = cc >> 4, c8 = (cc & 15) * 8;
                int grow = m0 + (lr >> 4) * 64 + t * 16 + (lr & 15);
                *(uint4*)((unsigned short*)Cmat + (size_t)grow * N + n0 + c8) =
                    *(const uint4*)&sm.ct[lr][c8];
            }
        }
    }
}

// ---------------------------------------------------------------------------
// RoPE in-place on bf16 X (8192 rows, stride elems/row, nh heads of 128).
// ---------------------------------------------------------------------------
__global__ __launch_bounds__(256) void k_rope(unsigned short* __restrict__ X,
                                              int lognh, int stride,
                                              const int* __restrict__ posPtr) {
    int tid = blockIdx.x * 256 + threadIdx.x;
    int d = tid & 63;
    int nh = 1 << lognh;
    int h = (tid >> 6) & (nh - 1);
    int row = tid >> (6 + lognh);
    int t = row & (TT - 1);
    float p = (float)(*posPtr + t);
    size_t base = (size_t)row * stride + h * 128 + d;
    union { unsigned int i; float f; } a, b2;
    a.i  = ((unsigned int)X[base]) << 16;
    b2.i = ((unsigned int)X[base + 64]) << 16;
    float x1 = a.f, x2 = b2.f;
    int i1 = d >> 1;
    float f1 = exp2f(-(float)i1 * 0.20762050595278f);
    float f2 = exp2f(-(float)(i1 + 32) * 0.20762050595278f);
    float th1 = p * f1, th2 = p * f2;
    X[base]      = f2b(x1 * cosf(th1) - x2 * sinf(th1));
    X[base + 64] = f2b(x2 * cosf(th2) + x1 * sinf(th2));
}

// ---------------------------------------------------------------------------
// Flash attention, causal, GQA (16 q / 4 kv heads). 512 threads, QBLK=128,
// paired q-tiles (i, 15-i); double-buffered K/V LDS, one barrier per K-step,
// register prefetch post-barrier; inactive-tile skip; interior fast path;
// T13 defer-max THR=8.
// ---------------------------------------------------------------------------
__device__ __forceinline__ void flash_pass(
    int qbase, int b, int h, int kvh,
    const unsigned short* __restrict__ QKV,
    const unsigned short* __restrict__ VbT,
    unsigned short* __restrict__ att,
    unsigned short (&Ks)[2][32][136],
    unsigned short (&Vt)[2][128][40],
    unsigned short (&Pt)[8][16][40]) {

    int tid = threadIdx.x;
    int w = tid >> 6, lane = tid & 63, quad = lane >> 4, l15 = lane & 15;

    bfrag qf[4];
    {
        size_t qrow = (size_t)(b * TT + qbase + w * 16 + l15);
        for (int kc = 0; kc < 4; ++kc)
            qf[kc] = *(const bfrag*)(QKV + qrow * 3072 + h * 128 + kc * 32 + quad * 8);
    }

    float mrow[4], lrow[4];
    facc o[8];
    for (int r = 0; r < 4; ++r) { mrow[r] = NEG_BIG; lrow[r] = 0.f; }
    for (int nb2 = 0; nb2 < 8; ++nb2)
        for (int r = 0; r < 4; ++r) o[nb2][r] = 0.f;

    int krow = tid >> 4, d8 = (tid & 15) * 8;
    int vd = tid >> 2, tc = (tid & 3) * 8;
    const unsigned short* Kg = QKV + (size_t)(b * TT) * 3072 + 2048 + kvh * 128;
    const unsigned short* Vg = VbT + (size_t)(kvh * 128 + vd) * 8192 + b * TT;

    const float sc = 0.08838834764831845f;   // 1/sqrt(128)
    int kmax = qbase + 128;
    int nt = kmax >> 5;
    int qgmin = qbase + w * 16;

    uint4 rk = *(const uint4*)(Kg + (size_t)krow * 3072 + d8);
    uint4 rv = *(const uint4*)(Vg + tc);

    for (int t = 0; t < nt; ++t) {
        int cur = t & 1;
        int k0 = t * 32;
        *(uint4*)&Ks[cur][krow][d8] = rk;
        *(uint4*)&Vt[cur][vd][tc]   = rv;
        __syncthreads();

        if (t + 1 < nt) {
            int k0n = k0 + 32;
            rk = *(const uint4*)(Kg + (size_t)(k0n + krow) * 3072 + d8);
            rv = *(const uint4*)(Vg + k0n + tc);
        }

        if (k0 > qgmin + 15) continue;

        facc s[2];
        for (int nb = 0; nb < 2; ++nb) {
            for (int r = 0; r < 4; ++r) s[nb][r] = 0.f;
            for (int kc = 0; kc < 4; ++kc) {
                bfrag kf = *(const bfrag*)&Ks[cur][nb * 16 + l15][kc * 32 + quad * 8];
                s[nb] = __builtin_amdgcn_mfma_f32_16x16x32_bf16(qf[kc], kf, s[nb], 0, 0, 0);
            }
        }

        bool fullT = (k0 + 31) <= qgmin;
        float alpha[4];
        int growAny = 0;
        for (int r = 0; r < 4; ++r) {
            float v0, v1;
            if (fullT) {
                v0 = s[0][r] * sc;
                v1 = s[1][r] * sc;
            } else {
                int qg = qgmin + quad * 4 + r;
                v0 = (k0 + l15 > qg)      ? NEG_BIG : s[0][r] * sc;
                v1 = (k0 + 16 + l15 > qg) ? NEG_BIG : s[1][r] * sc;
            }
            float mx = fmaxf(v0, v1);
            for (int off = 1; off < 16; off <<= 1) mx = fmaxf(mx, __shfl_xor(mx, off, 64));
            bool need = (mx > mrow[r] + 8.f);     // T13 defer-max, THR=8
            float mnew = need ? mx : mrow[r];
            growAny |= need;
            alpha[r] = need ? __expf(mrow[r] - mnew) : 1.f;
            float p0 = __expf(v0 - mnew);
            float p1 = __expf(v1 - mnew);
            float psum = p0 + p1;
            for (int off = 1; off < 16; off <<= 1) psum += __shfl_xor(psum, off, 64);
            lrow[r] = lrow[r] * alpha[r] + psum;
            mrow[r] = mnew;
            Pt[w][quad * 4 + r][l15]      = f2b(p0);
            Pt[w][quad * 4 + r][16 + l15] = f2b(p1);
        }
        if (__any(growAny)) {
            for (int nb2 = 0; nb2 < 8; ++nb2)
                for (int r = 0; r < 4; ++r) o[nb2][r] *= alpha[r];
        }

        asm volatile("s_waitcnt lgkmcnt(0)" ::: "memory");   // wave-local RAW on Pt[w]
        bfrag pf = *(const bfrag*)&Pt[w][l15][quad * 8];
        for (int nb2 = 0; nb2 < 8; ++nb2) {
            bfrag vf = *(const bfrag*)&Vt[cur][nb2 * 16 + l15][quad * 8];
            o[nb2] = __builtin_amdgcn_mfma_f32_16x16x32_bf16(pf, vf, o[nb2], 0, 0, 0);
        }
    }

    for (int nb2 = 0; nb2 < 8; ++nb2)
        for (int r = 0; r < 4; ++r) {
            int qg = qbase + w * 16 + quad * 4 + r;
            att[(size_t)(b * TT + qg) * 2048 + h * 128 + nb2 * 16 + l15] =
                f2b(o[nb2][r] / lrow[r]);
        }
}

__global__ __launch_bounds__(512, 4) void k_flash(const unsigned short* __restrict__ QKV,
                                                  const unsigned short* __restrict__ VbT,
                                                  unsigned short* __restrict__ att) {
    __shared__ alignas(16) unsigned short Ks[2][32][136];
    __shared__ alignas(16) unsigned short Vt[2][128][40];
    __shared__ alignas(16) unsigned short Pt[8][16][40];
    int bh = blockIdx.y;
    int b = bh >> 4, h = bh & 15;
    int kvh = h >> 2;
    int i = blockIdx.x;

    flash_pass(i * 128, b, h, kvh, QKV, VbT, att, Ks, Vt, Pt);
    __syncthreads();
    flash_pass((15 - i) * 128, b, h, kvh, QKV, VbT, att, Ks, Vt, Pt);
}

// ---------------------------------------------------------------------------
extern "C" void kernel_launch(void* const* d_in, const int* in_sizes, int n_in,
                              void* d_out, int out_size, void* d_ws, size_t ws_size,
                              hipStream_t stream) {
    const float* x  = (const float*)d_in[0];
    const float* Wq = (const float*)d_in[1];
    const float* Wk = (const float*)d_in[2];
    const float* Wv = (const float*)d_in[3];
    const float* Wo = (const float*)d_in[4];
    const int* pos  = (const int*)d_in[5];

    char* ws = (char*)d_ws;
    unsigned short* xb   = (unsigned short*)(ws + 0);          // 32 MB (8192x2048); reused as att out
    unsigned short* QKV  = (unsigned short*)(ws + 33554432);   // 48 MB (8192x3072)
    unsigned short* VbT  = (unsigned short*)(ws + 83886080);   //  8 MB (512x8192)
    unsigned short* WqT  = (unsigned short*)(ws + 92274688);   //  8 MB (2048x2048)
    unsigned short* WkvT = (unsigned short*)(ws + 100663296);  //  4 MB (1024x2048) -- contiguous with WqT
    unsigned short* WoT  = (unsigned short*)(ws + 104857600);  //  8 MB -> 108 MB total

    // bf16 conversion + weight transposes (WqT|WkvT form one contiguous 3072x2048 Bt)
    k_cvt<<<8192, 256, 0, stream>>>(x, xb, 2097152);
    k_wt<<<dim3(32, 32), 256, 0, stream>>>(Wq, WqT, 2048);
    k_wt<<<dim3(8, 32),  256, 0, stream>>>(Wk, WkvT, 512);
    k_wt<<<dim3(8, 32),  256, 0, stream>>>(Wv, WkvT + (size_t)512 * 2048, 512);
    k_wt<<<dim3(32, 32), 256, 0, stream>>>(Wo, WoT, 2048);

    // fused Q|K|V projection: 256x256 8-phase (spill-fixed) -- experimental arm
    k_gemm256<<<dim3(12, 32), 512, 0, stream>>>(xb, WqT, QKV, 8192, 3072, 2048, 0);

    // RoPE (Q: 16 heads, cols 0..2047; K: 4 heads, cols 2048..2559; stride 3072)
    k_rope<<<32768, 256, 0, stream>>>(QKV, 4, 3072, pos);
    k_rope<<<8192,  256, 0, stream>>>(QKV + 2048, 2, 3072, pos);

    // V transpose for flash B-frag staging
    k_vt<<<dim3(8, 128), 256, 0, stream>>>(QKV, VbT);

    // causal GQA flash attention -> xb (x no longer needed)
    k_flash<<<dim3(8, 64), 512, 0, stream>>>(QKV, VbT, xb);

    // output projection -> fp32 d_out: proven m97 BK=64 arm
    k_gemm_bt<64><<<dim3(16, 64), 256, 0, stream>>>(xb, WoT, d_out, 8192, 2048, 2048, 1);
}

// Round 6
// 707.245 us; speedup vs baseline: 1.1069x; 1.1069x over previous
//
#include <hip/hip_runtime.h>
#include <math.h>

#define TT 2048

typedef __attribute__((ext_vector_type(8))) short bfrag;   // 8 bf16 in 4 VGPRs
typedef __attribute__((ext_vector_type(4))) float facc;    // 4 fp32 acc

#define NEG_BIG (-1.0e30f)

typedef __attribute__((address_space(1))) const void gas_void;
typedef __attribute__((address_space(3))) void las_void;

__device__ __forceinline__ void gl_lds16(const void* g, void* l) {
    __builtin_amdgcn_global_load_lds((gas_void*)g, (las_void*)l, 16, 0, 0);
}

__device__ __forceinline__ unsigned short f2b(float f) {
    union { float f; unsigned int i; } v; v.f = f;
    unsigned int b = v.i;
    return (unsigned short)((b + 0x7FFFu + ((b >> 16) & 1u)) >> 16);  // RNE
}
__device__ __forceinline__ void cvt8_f32(const float* __restrict__ p, unsigned short* d) {
    float4 lo = *(const float4*)p, hi = *(const float4*)(p + 4);
    d[0] = f2b(lo.x); d[1] = f2b(lo.y); d[2] = f2b(lo.z); d[3] = f2b(lo.w);
    d[4] = f2b(hi.x); d[5] = f2b(hi.y); d[6] = f2b(hi.z); d[7] = f2b(hi.w);
}

// ---------------------------------------------------------------------------
// fp32 -> bf16 flat convert (n8 = count of 8-element chunks)
// ---------------------------------------------------------------------------
__global__ __launch_bounds__(256) void k_cvt(const float* __restrict__ in,
                                             unsigned short* __restrict__ out, int n8) {
    int c = blockIdx.x * 256 + threadIdx.x;
    if (c < n8) {
        unsigned short t[8];
        cvt8_f32(in + (size_t)c * 8, t);
        *(uint4*)(out + (size_t)c * 8) = *(const uint4*)t;
    }
}

// ---------------------------------------------------------------------------
// Weight transpose+convert: W (2048 x N fp32, row-major) -> WT (N x 2048 bf16)
// ---------------------------------------------------------------------------
__global__ __launch_bounds__(256) void k_wt(const float* __restrict__ W,
                                            unsigned short* __restrict__ WT, int N) {
    __shared__ alignas(16) unsigned short tile[64][72];
    int r0 = blockIdx.y * 64, c0 = blockIdx.x * 64;
    int tid = threadIdx.x;
    for (int i = 0; i < 2; ++i) {
        int c = tid + i * 256;
        int row = c >> 3, c8 = (c & 7) * 8;
        unsigned short t[8];
        cvt8_f32(W + (size_t)(r0 + row) * N + c0 + c8, t);
        *(uint4*)&tile[row][c8] = *(const uint4*)t;
    }
    __syncthreads();
    for (int i = 0; i < 2; ++i) {
        int c = tid + i * 256;
        int col = c >> 3, r8 = (c & 7) * 8;
        unsigned short t[8];
        for (int j = 0; j < 8; ++j) t[j] = tile[r8 + j][col];
        *(uint4*)(WT + (size_t)(c0 + col) * 2048 + r0 + r8) = *(const uint4*)t;
    }
}

// ---------------------------------------------------------------------------
// V transpose: QKV (8192 x 3072 bf16, V = cols 2560..3071) -> VbT (512 x 8192)
// ---------------------------------------------------------------------------
__global__ __launch_bounds__(256) void k_vt(const unsigned short* __restrict__ QKV,
                                            unsigned short* __restrict__ VbT) {
    __shared__ alignas(16) unsigned short tile[64][72];
    int r0 = blockIdx.y * 64, c0 = blockIdx.x * 64;
    int tid = threadIdx.x;
    for (int i = 0; i < 2; ++i) {
        int c = tid + i * 256;
        int row = c >> 3, c8 = (c & 7) * 8;
        *(uint4*)&tile[row][c8] =
            *(const uint4*)(QKV + (size_t)(r0 + row) * 3072 + 2560 + c0 + c8);
    }
    __syncthreads();
    for (int i = 0; i < 2; ++i) {
        int c = tid + i * 256;
        int col = c >> 3, r8 = (c & 7) * 8;
        unsigned short t[8];
        for (int j = 0; j < 8; ++j) t[j] = tile[r8 + j][col];
        *(uint4*)(VbT + (size_t)(c0 + col) * 8192 + r0 + r8) = *(const uint4*)t;
    }
}

// ---------------------------------------------------------------------------
// 2-phase double-buffered m97 GEMM (T3 minimum recipe): identical geometry,
// staging and swizzle to the proven BK=64 k_gemm_bt, but:
//   - LDS double-buffered (2 x 16KB x {A,B} = 64 KB -> 2 blocks/CU)
//   - next tile's global_load_lds issued BEFORE current tile's ds_read+MFMA
//   - ONE __syncthreads per K-tile (its implicit vmcnt(0) lands ~a full
//     compute phase after load issue, instead of immediately after)
// No inline-asm waits: fully compiler-managed. Race safety: tile t reads
// buf[cur] (ds_reads complete before barrier) while DMA fills buf[cur^1];
// buf[cur] is only overwritten after the barrier.
// ---------------------------------------------------------------------------
__global__ __launch_bounds__(256) void k_gemm2ph(const unsigned short* __restrict__ A,
                                                 const unsigned short* __restrict__ Bt,
                                                 void* __restrict__ Cmat,
                                                 int M, int N, int K, int outF) {
    __shared__ union SM {
        struct { unsigned short A[2][128][64]; unsigned short B[2][128][64]; } s;  // 64 KB
        unsigned short ct[32][136];
        float          ctf[32][136];
    } sm;
    int tid = threadIdx.x;
    int w = tid >> 6, lane = tid & 63, quad = lane >> 4, l15 = lane & 15;
    int m0 = blockIdx.y * 128, n0 = blockIdx.x * 128;
    int wm = (w >> 1) * 64, wn = (w & 1) * 64;

    int srow   = lane >> 3;                 // 0..7
    int schunk = (lane & 7) ^ (lane >> 3);  // inverse-swizzled source chunk

    facc acc[4][4];
#pragma unroll
    for (int mi = 0; mi < 4; ++mi)
#pragma unroll
        for (int ni = 0; ni < 4; ++ni)
#pragma unroll
            for (int r = 0; r < 4; ++r) acc[mi][ni][r] = 0.f;

    auto stage = [&](int bb, int k0) {
#pragma unroll
        for (int i = 0; i < 4; ++i) {
            int row = w * 32 + i * 8;
            gl_lds16(A  + (size_t)(m0 + row + srow) * K + k0 + schunk * 8, &sm.s.A[bb][row][0]);
            gl_lds16(Bt + (size_t)(n0 + row + srow) * K + k0 + schunk * 8, &sm.s.B[bb][row][0]);
        }
    };

    int NT = K >> 6;
    stage(0, 0);
    __syncthreads();                        // implicit vmcnt(0): buf0 ready

    for (int t = 0; t < NT; ++t) {
        int cur = t & 1;
        if (t + 1 < NT) stage(cur ^ 1, (t + 1) * 64);   // hide under compute

        bfrag af[4][2], bf[4][2];
#pragma unroll
        for (int mi = 0; mi < 4; ++mi)
#pragma unroll
            for (int kc = 0; kc < 2; ++kc)
                af[mi][kc] = *(const bfrag*)&sm.s.A[cur][wm + mi * 16 + l15][((kc * 4 + quad) ^ (l15 & 7)) * 8];
#pragma unroll
        for (int ni = 0; ni < 4; ++ni)
#pragma unroll
            for (int kc = 0; kc < 2; ++kc)
                bf[ni][kc] = *(const bfrag*)&sm.s.B[cur][wn + ni * 16 + l15][((kc * 4 + quad) ^ (l15 & 7)) * 8];
#pragma unroll
        for (int kc = 0; kc < 2; ++kc)
#pragma unroll
            for (int mi = 0; mi < 4; ++mi)
#pragma unroll
                for (int ni = 0; ni < 4; ++ni)
                    acc[mi][ni] = __builtin_amdgcn_mfma_f32_16x16x32_bf16(af[mi][kc], bf[ni][kc], acc[mi][ni], 0, 0, 0);

        __syncthreads();                    // drains vmcnt (t+1 staged) + fences buf[cur]
    }

    // epilogue: 4 rounds; round t stages every wave's mi=t subtile (32x128)
#pragma unroll
    for (int t = 0; t < 4; ++t) {
        __syncthreads();
#pragma unroll
        for (int ni = 0; ni < 4; ++ni)
#pragma unroll
            for (int r = 0; r < 4; ++r) {
                int lr = (w >> 1) * 16 + quad * 4 + r;
                int lc = wn + ni * 16 + l15;
                if (outF) sm.ctf[lr][lc] = acc[t][ni][r];
                else      sm.ct [lr][lc] = f2b(acc[t][ni][r]);
            }
        __syncthreads();
        if (outF) {
#pragma unroll
            for (int i = 0; i < 4; ++i) {
                int cc = tid + i * 256;
                int lr = cc >> 5, c4 = (cc & 31) * 4;
                int grow = m0 + (lr >> 4) * 64 + t * 16 + (lr & 15);
                *(float4*)((float*)Cmat + (size_t)grow * N + n0 + c4) =
                    *(const float4*)&sm.ctf[lr][c4];
            }
        } else {
#pragma unroll
            for (int i = 0; i < 2; ++i) {
                int cc = tid + i * 256;
                int lr = cc >> 4, c8 = (cc & 15) * 8;
                int grow = m0 + (lr >> 4) * 64 + t * 16 + (lr & 15);
                *(uint4*)((unsigned short*)Cmat + (size_t)grow * N + n0 + c8) =
                    *(const uint4*)&sm.ct[lr][c8];
            }
        }
    }
}

// ---------------------------------------------------------------------------
// m97-style GEMM, BK=64 (round-4 A/B winner) -- proven arm, O-projection.
// ---------------------------------------------------------------------------
template <int BK>
__global__ __launch_bounds__(256) void k_gemm_bt(const unsigned short* __restrict__ A,
                                                 const unsigned short* __restrict__ Bt,
                                                 void* __restrict__ Cmat,
                                                 int M, int N, int K, int outF) {
    __shared__ union SM {
        struct { unsigned short A[128][BK]; unsigned short B[128][BK]; } s;
        unsigned short ct[32][136];
        float          ctf[32][136];
    } sm;
    int tid = threadIdx.x;
    int w = tid >> 6, lane = tid & 63, quad = lane >> 4, l15 = lane & 15;
    int m0 = blockIdx.y * 128, n0 = blockIdx.x * 128;
    int wm = (w >> 1) * 64, wn = (w & 1) * 64;

    facc acc[4][4];
    for (int mi = 0; mi < 4; ++mi)
        for (int ni = 0; ni < 4; ++ni)
            for (int r = 0; r < 4; ++r) acc[mi][ni][r] = 0.f;

    int srow   = lane >> 3;                       // 0..7
    int schunk = (lane & 7) ^ (lane >> 3);

    for (int k0 = 0; k0 < K; k0 += 64) {
        for (int i = 0; i < 4; ++i) {
            int row = w * 32 + i * 8;
            gl_lds16(A  + (size_t)(m0 + row + srow) * K + k0 + schunk * 8, &sm.s.A[row][0]);
            gl_lds16(Bt + (size_t)(n0 + row + srow) * K + k0 + schunk * 8, &sm.s.B[row][0]);
        }
        __syncthreads();
        bfrag af[4][2], bf[4][2];
        for (int mi = 0; mi < 4; ++mi)
            for (int kc = 0; kc < 2; ++kc)
                af[mi][kc] = *(const bfrag*)&sm.s.A[wm + mi * 16 + l15][((kc * 4 + quad) ^ (l15 & 7)) * 8];
        for (int ni = 0; ni < 4; ++ni)
            for (int kc = 0; kc < 2; ++kc)
                bf[ni][kc] = *(const bfrag*)&sm.s.B[wn + ni * 16 + l15][((kc * 4 + quad) ^ (l15 & 7)) * 8];
        for (int kc = 0; kc < 2; ++kc)
            for (int mi = 0; mi < 4; ++mi)
                for (int ni = 0; ni < 4; ++ni)
                    acc[mi][ni] = __builtin_amdgcn_mfma_f32_16x16x32_bf16(af[mi][kc], bf[ni][kc], acc[mi][ni], 0, 0, 0);
        __syncthreads();
    }

    for (int t = 0; t < 4; ++t) {
        __syncthreads();
        for (int ni = 0; ni < 4; ++ni)
            for (int r = 0; r < 4; ++r) {
                int lr = (w >> 1) * 16 + quad * 4 + r;
                int lc = wn + ni * 16 + l15;
                if (outF) sm.ctf[lr][lc] = acc[t][ni][r];
                else      sm.ct [lr][lc] = f2b(acc[t][ni][r]);
            }
        __syncthreads();
        if (outF) {
            for (int i = 0; i < 4; ++i) {
                int cc = tid + i * 256;
                int lr = cc >> 5, c4 = (cc & 31) * 4;
                int grow = m0 + (lr >> 4) * 64 + t * 16 + (lr & 15);
                *(float4*)((float*)Cmat + (size_t)grow * N + n0 + c4) =
                    *(const float4*)&sm.ctf[lr][c4];
            }
        } else {
            for (int i = 0; i < 2; ++i) {
                int cc = tid + i * 256;
                int lr = cc >> 4, c8 = (cc & 15) * 8;
                int grow = m0 + (lr >> 4) * 64 + t * 16 + (lr & 15);
                *(uint4*)((unsigned short*)Cmat + (size_t)grow * N + n0 + c8) =
                    *(const uint4*)&sm.ct[lr][c8];
            }
        }
    }
}

// ---------------------------------------------------------------------------
// RoPE in-place on bf16 X (8192 rows, stride elems/row, nh heads of 128).
// ---------------------------------------------------------------------------
__global__ __launch_bounds__(256) void k_rope(unsigned short* __restrict__ X,
                                              int lognh, int stride,
                                              const int* __restrict__ posPtr) {
    int tid = blockIdx.x * 256 + threadIdx.x;
    int d = tid & 63;
    int nh = 1 << lognh;
    int h = (tid >> 6) & (nh - 1);
    int row = tid >> (6 + lognh);
    int t = row & (TT - 1);
    float p = (float)(*posPtr + t);
    size_t base = (size_t)row * stride + h * 128 + d;
    union { unsigned int i; float f; } a, b2;
    a.i  = ((unsigned int)X[base]) << 16;
    b2.i = ((unsigned int)X[base + 64]) << 16;
    float x1 = a.f, x2 = b2.f;
    int i1 = d >> 1;
    float f1 = exp2f(-(float)i1 * 0.20762050595278f);
    float f2 = exp2f(-(float)(i1 + 32) * 0.20762050595278f);
    float th1 = p * f1, th2 = p * f2;
    X[base]      = f2b(x1 * cosf(th1) - x2 * sinf(th1));
    X[base + 64] = f2b(x2 * cosf(th2) + x1 * sinf(th2));
}

// ---------------------------------------------------------------------------
// Flash attention, causal, GQA (16 q / 4 kv heads). 512 threads, QBLK=128,
// paired q-tiles (i, 15-i); double-buffered K/V LDS, one barrier per K-step,
// register prefetch post-barrier; inactive-tile skip; interior fast path;
// T13 defer-max THR=8.
// ---------------------------------------------------------------------------
__device__ __forceinline__ void flash_pass(
    int qbase, int b, int h, int kvh,
    const unsigned short* __restrict__ QKV,
    const unsigned short* __restrict__ VbT,
    unsigned short* __restrict__ att,
    unsigned short (&Ks)[2][32][136],
    unsigned short (&Vt)[2][128][40],
    unsigned short (&Pt)[8][16][40]) {

    int tid = threadIdx.x;
    int w = tid >> 6, lane = tid & 63, quad = lane >> 4, l15 = lane & 15;

    bfrag qf[4];
    {
        size_t qrow = (size_t)(b * TT + qbase + w * 16 + l15);
        for (int kc = 0; kc < 4; ++kc)
            qf[kc] = *(const bfrag*)(QKV + qrow * 3072 + h * 128 + kc * 32 + quad * 8);
    }

    float mrow[4], lrow[4];
    facc o[8];
    for (int r = 0; r < 4; ++r) { mrow[r] = NEG_BIG; lrow[r] = 0.f; }
    for (int nb2 = 0; nb2 < 8; ++nb2)
        for (int r = 0; r < 4; ++r) o[nb2][r] = 0.f;

    int krow = tid >> 4, d8 = (tid & 15) * 8;
    int vd = tid >> 2, tc = (tid & 3) * 8;
    const unsigned short* Kg = QKV + (size_t)(b * TT) * 3072 + 2048 + kvh * 128;
    const unsigned short* Vg = VbT + (size_t)(kvh * 128 + vd) * 8192 + b * TT;

    const float sc = 0.08838834764831845f;   // 1/sqrt(128)
    int kmax = qbase + 128;
    int nt = kmax >> 5;
    int qgmin = qbase + w * 16;

    uint4 rk = *(const uint4*)(Kg + (size_t)krow * 3072 + d8);
    uint4 rv = *(const uint4*)(Vg + tc);

    for (int t = 0; t < nt; ++t) {
        int cur = t & 1;
        int k0 = t * 32;
        *(uint4*)&Ks[cur][krow][d8] = rk;
        *(uint4*)&Vt[cur][vd][tc]   = rv;
        __syncthreads();

        if (t + 1 < nt) {
            int k0n = k0 + 32;
            rk = *(const uint4*)(Kg + (size_t)(k0n + krow) * 3072 + d8);
            rv = *(const uint4*)(Vg + k0n + tc);
        }

        if (k0 > qgmin + 15) continue;

        facc s[2];
        for (int nb = 0; nb < 2; ++nb) {
            for (int r = 0; r < 4; ++r) s[nb][r] = 0.f;
            for (int kc = 0; kc < 4; ++kc) {
                bfrag kf = *(const bfrag*)&Ks[cur][nb * 16 + l15][kc * 32 + quad * 8];
                s[nb] = __builtin_amdgcn_mfma_f32_16x16x32_bf16(qf[kc], kf, s[nb], 0, 0, 0);
            }
        }

        bool fullT = (k0 + 31) <= qgmin;
        float alpha[4];
        int growAny = 0;
        for (int r = 0; r < 4; ++r) {
            float v0, v1;
            if (fullT) {
                v0 = s[0][r] * sc;
                v1 = s[1][r] * sc;
            } else {
                int qg = qgmin + quad * 4 + r;
                v0 = (k0 + l15 > qg)      ? NEG_BIG : s[0][r] * sc;
                v1 = (k0 + 16 + l15 > qg) ? NEG_BIG : s[1][r] * sc;
            }
            float mx = fmaxf(v0, v1);
            for (int off = 1; off < 16; off <<= 1) mx = fmaxf(mx, __shfl_xor(mx, off, 64));
            bool need = (mx > mrow[r] + 8.f);     // T13 defer-max, THR=8
            float mnew = need ? mx : mrow[r];
            growAny |= need;
            alpha[r] = need ? __expf(mrow[r] - mnew) : 1.f;
            float p0 = __expf(v0 - mnew);
            float p1 = __expf(v1 - mnew);
            float psum = p0 + p1;
            for (int off = 1; off < 16; off <<= 1) psum += __shfl_xor(psum, off, 64);
            lrow[r] = lrow[r] * alpha[r] + psum;
            mrow[r] = mnew;
            Pt[w][quad * 4 + r][l15]      = f2b(p0);
            Pt[w][quad * 4 + r][16 + l15] = f2b(p1);
        }
        if (__any(growAny)) {
            for (int nb2 = 0; nb2 < 8; ++nb2)
                for (int r = 0; r < 4; ++r) o[nb2][r] *= alpha[r];
        }

        asm volatile("s_waitcnt lgkmcnt(0)" ::: "memory");   // wave-local RAW on Pt[w]
        bfrag pf = *(const bfrag*)&Pt[w][l15][quad * 8];
        for (int nb2 = 0; nb2 < 8; ++nb2) {
            bfrag vf = *(const bfrag*)&Vt[cur][nb2 * 16 + l15][quad * 8];
            o[nb2] = __builtin_amdgcn_mfma_f32_16x16x32_bf16(pf, vf, o[nb2], 0, 0, 0);
        }
    }

    for (int nb2 = 0; nb2 < 8; ++nb2)
        for (int r = 0; r < 4; ++r) {
            int qg = qbase + w * 16 + quad * 4 + r;
            att[(size_t)(b * TT + qg) * 2048 + h * 128 + nb2 * 16 + l15] =
                f2b(o[nb2][r] / lrow[r]);
        }
}

__global__ __launch_bounds__(512, 4) void k_flash(const unsigned short* __restrict__ QKV,
                                                  const unsigned short* __restrict__ VbT,
                                                  unsigned short* __restrict__ att) {
    __shared__ alignas(16) unsigned short Ks[2][32][136];
    __shared__ alignas(16) unsigned short Vt[2][128][40];
    __shared__ alignas(16) unsigned short Pt[8][16][40];
    int bh = blockIdx.y;
    int b = bh >> 4, h = bh & 15;
    int kvh = h >> 2;
    int i = blockIdx.x;

    flash_pass(i * 128, b, h, kvh, QKV, VbT, att, Ks, Vt, Pt);
    __syncthreads();
    flash_pass((15 - i) * 128, b, h, kvh, QKV, VbT, att, Ks, Vt, Pt);
}

// ---------------------------------------------------------------------------
extern "C" void kernel_launch(void* const* d_in, const int* in_sizes, int n_in,
                              void* d_out, int out_size, void* d_ws, size_t ws_size,
                              hipStream_t stream) {
    const float* x  = (const float*)d_in[0];
    const float* Wq = (const float*)d_in[1];
    const float* Wk = (const float*)d_in[2];
    const float* Wv = (const float*)d_in[3];
    const float* Wo = (const float*)d_in[4];
    const int* pos  = (const int*)d_in[5];

    char* ws = (char*)d_ws;
    unsigned short* xb   = (unsigned short*)(ws + 0);          // 32 MB (8192x2048); reused as att out
    unsigned short* QKV  = (unsigned short*)(ws + 33554432);   // 48 MB (8192x3072)
    unsigned short* VbT  = (unsigned short*)(ws + 83886080);   //  8 MB (512x8192)
    unsigned short* WqT  = (unsigned short*)(ws + 92274688);   //  8 MB (2048x2048)
    unsigned short* WkvT = (unsigned short*)(ws + 100663296);  //  4 MB (1024x2048) -- contiguous with WqT
    unsigned short* WoT  = (unsigned short*)(ws + 104857600);  //  8 MB -> 108 MB total

    // bf16 conversion + weight transposes (WqT|WkvT form one contiguous 3072x2048 Bt)
    k_cvt<<<8192, 256, 0, stream>>>(x, xb, 2097152);
    k_wt<<<dim3(32, 32), 256, 0, stream>>>(Wq, WqT, 2048);
    k_wt<<<dim3(8, 32),  256, 0, stream>>>(Wk, WkvT, 512);
    k_wt<<<dim3(8, 32),  256, 0, stream>>>(Wv, WkvT + (size_t)512 * 2048, 512);
    k_wt<<<dim3(32, 32), 256, 0, stream>>>(Wo, WoT, 2048);

    // fused Q|K|V projection: 2-phase double-buffered (experimental arm)
    k_gemm2ph<<<dim3(24, 64), 256, 0, stream>>>(xb, WqT, QKV, 8192, 3072, 2048, 0);

    // RoPE (Q: 16 heads, cols 0..2047; K: 4 heads, cols 2048..2559; stride 3072)
    k_rope<<<32768, 256, 0, stream>>>(QKV, 4, 3072, pos);
    k_rope<<<8192,  256, 0, stream>>>(QKV + 2048, 2, 3072, pos);

    // V transpose for flash B-frag staging
    k_vt<<<dim3(8, 128), 256, 0, stream>>>(QKV, VbT);

    // causal GQA flash attention -> xb (x no longer needed)
    k_flash<<<dim3(8, 64), 512, 0, stream>>>(QKV, VbT, xb);

    // output projection -> fp32 d_out: proven m97 BK=64 arm
    k_gemm_bt<64><<<dim3(16, 64), 256, 0, stream>>>(xb, WoT, d_out, 8192, 2048, 2048, 1);
}

// Round 7
// 592.058 us; speedup vs baseline: 1.3222x; 1.1946x over previous
//
#include <hip/hip_runtime.h>
#include <math.h>

#define TT 2048

typedef __attribute__((ext_vector_type(8))) short bfrag;   // 8 bf16 in 4 VGPRs
typedef __attribute__((ext_vector_type(4))) float facc;    // 4 fp32 acc

#define NEG_BIG (-1.0e30f)

typedef __attribute__((address_space(1))) const void gas_void;
typedef __attribute__((address_space(3))) void las_void;

__device__ __forceinline__ void gl_lds16(const void* g, void* l) {
    __builtin_amdgcn_global_load_lds((gas_void*)g, (las_void*)l, 16, 0, 0);
}

__device__ __forceinline__ unsigned short f2b(float f) {
    union { float f; unsigned int i; } v; v.f = f;
    unsigned int b = v.i;
    return (unsigned short)((b + 0x7FFFu + ((b >> 16) & 1u)) >> 16);  // RNE
}
__device__ __forceinline__ void cvt8_f32(const float* __restrict__ p, unsigned short* d) {
    float4 lo = *(const float4*)p, hi = *(const float4*)(p + 4);
    d[0] = f2b(lo.x); d[1] = f2b(lo.y); d[2] = f2b(lo.z); d[3] = f2b(lo.w);
    d[4] = f2b(hi.x); d[5] = f2b(hi.y); d[6] = f2b(hi.z); d[7] = f2b(hi.w);
}

// ---------------------------------------------------------------------------
// fp32 -> bf16 flat convert (n8 = count of 8-element chunks)
// ---------------------------------------------------------------------------
__global__ __launch_bounds__(256) void k_cvt(const float* __restrict__ in,
                                             unsigned short* __restrict__ out, int n8) {
    int c = blockIdx.x * 256 + threadIdx.x;
    if (c < n8) {
        unsigned short t[8];
        cvt8_f32(in + (size_t)c * 8, t);
        *(uint4*)(out + (size_t)c * 8) = *(const uint4*)t;
    }
}

// ---------------------------------------------------------------------------
// Weight transpose+convert: W (2048 x N fp32, row-major) -> WT (N x 2048 bf16)
// ---------------------------------------------------------------------------
__global__ __launch_bounds__(256) void k_wt(const float* __restrict__ W,
                                            unsigned short* __restrict__ WT, int N) {
    __shared__ alignas(16) unsigned short tile[64][72];
    int r0 = blockIdx.y * 64, c0 = blockIdx.x * 64;
    int tid = threadIdx.x;
    for (int i = 0; i < 2; ++i) {
        int c = tid + i * 256;
        int row = c >> 3, c8 = (c & 7) * 8;
        unsigned short t[8];
        cvt8_f32(W + (size_t)(r0 + row) * N + c0 + c8, t);
        *(uint4*)&tile[row][c8] = *(const uint4*)t;
    }
    __syncthreads();
    for (int i = 0; i < 2; ++i) {
        int c = tid + i * 256;
        int col = c >> 3, r8 = (c & 7) * 8;
        unsigned short t[8];
        for (int j = 0; j < 8; ++j) t[j] = tile[r8 + j][col];
        *(uint4*)(WT + (size_t)(c0 + col) * 2048 + r0 + r8) = *(const uint4*)t;
    }
}

// ---------------------------------------------------------------------------
// V transpose: QKV (8192 x 3072 bf16, V = cols 2560..3071) -> VbT (512 x 8192)
// ---------------------------------------------------------------------------
__global__ __launch_bounds__(256) void k_vt(const unsigned short* __restrict__ QKV,
                                            unsigned short* __restrict__ VbT) {
    __shared__ alignas(16) unsigned short tile[64][72];
    int r0 = blockIdx.y * 64, c0 = blockIdx.x * 64;
    int tid = threadIdx.x;
    for (int i = 0; i < 2; ++i) {
        int c = tid + i * 256;
        int row = c >> 3, c8 = (c & 7) * 8;
        *(uint4*)&tile[row][c8] =
            *(const uint4*)(QKV + (size_t)(r0 + row) * 3072 + 2560 + c0 + c8);
    }
    __syncthreads();
    for (int i = 0; i < 2; ++i) {
        int c = tid + i * 256;
        int col = c >> 3, r8 = (c & 7) * 8;
        unsigned short t[8];
        for (int j = 0; j < 8; ++j) t[j] = tile[r8 + j][col];
        *(uint4*)(VbT + (size_t)(c0 + col) * 8192 + r0 + r8) = *(const uint4*)t;
    }
}

// ---------------------------------------------------------------------------
// 2-phase double-buffered m97 GEMM (round-6 winner: 517 TF on QKV).
// 128x128 tile, BK=64, 64 KB LDS dbuf, next tile's global_load_lds issued
// before current tile's ds_read+MFMA, ONE __syncthreads per K-tile.
// Used for BOTH projections now (outF=1 -> fp32 out).
// ---------------------------------------------------------------------------
__global__ __launch_bounds__(256) void k_gemm2ph(const unsigned short* __restrict__ A,
                                                 const unsigned short* __restrict__ Bt,
                                                 void* __restrict__ Cmat,
                                                 int M, int N, int K, int outF) {
    __shared__ union SM {
        struct { unsigned short A[2][128][64]; unsigned short B[2][128][64]; } s;  // 64 KB
        unsigned short ct[32][136];
        float          ctf[32][136];
    } sm;
    int tid = threadIdx.x;
    int w = tid >> 6, lane = tid & 63, quad = lane >> 4, l15 = lane & 15;
    int m0 = blockIdx.y * 128, n0 = blockIdx.x * 128;
    int wm = (w >> 1) * 64, wn = (w & 1) * 64;

    int srow   = lane >> 3;                 // 0..7
    int schunk = (lane & 7) ^ (lane >> 3);  // inverse-swizzled source chunk

    facc acc[4][4];
#pragma unroll
    for (int mi = 0; mi < 4; ++mi)
#pragma unroll
        for (int ni = 0; ni < 4; ++ni)
#pragma unroll
            for (int r = 0; r < 4; ++r) acc[mi][ni][r] = 0.f;

    auto stage = [&](int bb, int k0) {
#pragma unroll
        for (int i = 0; i < 4; ++i) {
            int row = w * 32 + i * 8;
            gl_lds16(A  + (size_t)(m0 + row + srow) * K + k0 + schunk * 8, &sm.s.A[bb][row][0]);
            gl_lds16(Bt + (size_t)(n0 + row + srow) * K + k0 + schunk * 8, &sm.s.B[bb][row][0]);
        }
    };

    int NT = K >> 6;
    stage(0, 0);
    __syncthreads();                        // implicit vmcnt(0): buf0 ready

    for (int t = 0; t < NT; ++t) {
        int cur = t & 1;
        if (t + 1 < NT) stage(cur ^ 1, (t + 1) * 64);   // hide under compute

        bfrag af[4][2], bf[4][2];
#pragma unroll
        for (int mi = 0; mi < 4; ++mi)
#pragma unroll
            for (int kc = 0; kc < 2; ++kc)
                af[mi][kc] = *(const bfrag*)&sm.s.A[cur][wm + mi * 16 + l15][((kc * 4 + quad) ^ (l15 & 7)) * 8];
#pragma unroll
        for (int ni = 0; ni < 4; ++ni)
#pragma unroll
            for (int kc = 0; kc < 2; ++kc)
                bf[ni][kc] = *(const bfrag*)&sm.s.B[cur][wn + ni * 16 + l15][((kc * 4 + quad) ^ (l15 & 7)) * 8];
#pragma unroll
        for (int kc = 0; kc < 2; ++kc)
#pragma unroll
            for (int mi = 0; mi < 4; ++mi)
#pragma unroll
                for (int ni = 0; ni < 4; ++ni)
                    acc[mi][ni] = __builtin_amdgcn_mfma_f32_16x16x32_bf16(af[mi][kc], bf[ni][kc], acc[mi][ni], 0, 0, 0);

        __syncthreads();                    // drains vmcnt (t+1 staged) + fences buf[cur]
    }

    // epilogue: 4 rounds; round t stages every wave's mi=t subtile (32x128)
#pragma unroll
    for (int t = 0; t < 4; ++t) {
        __syncthreads();
#pragma unroll
        for (int ni = 0; ni < 4; ++ni)
#pragma unroll
            for (int r = 0; r < 4; ++r) {
                int lr = (w >> 1) * 16 + quad * 4 + r;
                int lc = wn + ni * 16 + l15;
                if (outF) sm.ctf[lr][lc] = acc[t][ni][r];
                else      sm.ct [lr][lc] = f2b(acc[t][ni][r]);
            }
        __syncthreads();
        if (outF) {
#pragma unroll
            for (int i = 0; i < 4; ++i) {
                int cc = tid + i * 256;
                int lr = cc >> 5, c4 = (cc & 31) * 4;
                int grow = m0 + (lr >> 4) * 64 + t * 16 + (lr & 15);
                *(float4*)((float*)Cmat + (size_t)grow * N + n0 + c4) =
                    *(const float4*)&sm.ctf[lr][c4];
            }
        } else {
#pragma unroll
            for (int i = 0; i < 2; ++i) {
                int cc = tid + i * 256;
                int lr = cc >> 4, c8 = (cc & 15) * 8;
                int grow = m0 + (lr >> 4) * 64 + t * 16 + (lr & 15);
                *(uint4*)((unsigned short*)Cmat + (size_t)grow * N + n0 + c8) =
                    *(const uint4*)&sm.ct[lr][c8];
            }
        }
    }
}

// ---------------------------------------------------------------------------
// RoPE in-place on bf16 X (8192 rows, stride elems/row, nh heads of 128).
// ---------------------------------------------------------------------------
__global__ __launch_bounds__(256) void k_rope(unsigned short* __restrict__ X,
                                              int lognh, int stride,
                                              const int* __restrict__ posPtr) {
    int tid = blockIdx.x * 256 + threadIdx.x;
    int d = tid & 63;
    int nh = 1 << lognh;
    int h = (tid >> 6) & (nh - 1);
    int row = tid >> (6 + lognh);
    int t = row & (TT - 1);
    float p = (float)(*posPtr + t);
    size_t base = (size_t)row * stride + h * 128 + d;
    union { unsigned int i; float f; } a, b2;
    a.i  = ((unsigned int)X[base]) << 16;
    b2.i = ((unsigned int)X[base + 64]) << 16;
    float x1 = a.f, x2 = b2.f;
    int i1 = d >> 1;
    float f1 = exp2f(-(float)i1 * 0.20762050595278f);
    float f2 = exp2f(-(float)(i1 + 32) * 0.20762050595278f);
    float th1 = p * f1, th2 = p * f2;
    X[base]      = f2b(x1 * cosf(th1) - x2 * sinf(th1));
    X[base + 64] = f2b(x2 * cosf(th2) + x1 * sinf(th2));
}

// ---------------------------------------------------------------------------
// Flash attention, causal, GQA (16 q / 4 kv heads). 512 threads, QBLK=128,
// paired q-tiles (i, 15-i); double-buffered K/V LDS, one barrier per K-step,
// register prefetch post-barrier; inactive-tile skip; interior fast path;
// T13 defer-max THR=8.
// NEW (T12-style): SWAPPED QK^T -- s = mfma(K, Q) puts q in l15 and k in
// (nb,quad,r). Each lane owns 8 P-values of ONE q-row -> row max/sum are
// 7 local ops + TWO shfl_xor (quad-fold 16/32) instead of 2x4-step 16-lane
// reductions: 32 shuffles/K-step -> 4. Softmax state (m,l) = 2 scalars/lane
// (q = qgmin + l15). P->LDS round-trip absorbs the layout change: lane
// writes 2x 8B (4 contiguous k per nb) to Pt[w][l15][nb*16+quad*4]; the
// PV-side pf read and o layout are UNCHANGED. Rescale / final divide fetch
// per-q state via one width-16 shfl per r (rescale ~never fires after
// tile 0; divide once per pass).
// ---------------------------------------------------------------------------
__device__ __forceinline__ void flash_pass(
    int qbase, int b, int h, int kvh,
    const unsigned short* __restrict__ QKV,
    const unsigned short* __restrict__ VbT,
    unsigned short* __restrict__ att,
    unsigned short (&Ks)[2][32][136],
    unsigned short (&Vt)[2][128][40],
    unsigned short (&Pt)[8][16][40]) {

    int tid = threadIdx.x;
    int w = tid >> 6, lane = tid & 63, quad = lane >> 4, l15 = lane & 15;

    // Q fragments: same bytes serve as the B operand of the swapped MFMA
    // (B-frag lane mapping == Q^T's natural layout).
    bfrag qf[4];
    {
        size_t qrow = (size_t)(b * TT + qbase + w * 16 + l15);
        for (int kc = 0; kc < 4; ++kc)
            qf[kc] = *(const bfrag*)(QKV + qrow * 3072 + h * 128 + kc * 32 + quad * 8);
    }

    float mreg = NEG_BIG, lreg = 0.f;      // state for q = qgmin + l15
    facc o[8];
#pragma unroll
    for (int nb2 = 0; nb2 < 8; ++nb2)
#pragma unroll
        for (int r = 0; r < 4; ++r) o[nb2][r] = 0.f;

    int krow = tid >> 4, d8 = (tid & 15) * 8;
    int vd = tid >> 2, tc = (tid & 3) * 8;
    const unsigned short* Kg = QKV + (size_t)(b * TT) * 3072 + 2048 + kvh * 128;
    const unsigned short* Vg = VbT + (size_t)(kvh * 128 + vd) * 8192 + b * TT;

    const float sc = 0.08838834764831845f;   // 1/sqrt(128)
    int kmax = qbase + 128;
    int nt = kmax >> 5;
    int qgmin = qbase + w * 16;
    int myq = qgmin + l15;                   // this lane's q-row

    uint4 rk = *(const uint4*)(Kg + (size_t)krow * 3072 + d8);
    uint4 rv = *(const uint4*)(Vg + tc);

    for (int t = 0; t < nt; ++t) {
        int cur = t & 1;
        int k0 = t * 32;
        *(uint4*)&Ks[cur][krow][d8] = rk;
        *(uint4*)&Vt[cur][vd][tc]   = rv;
        __syncthreads();

        if (t + 1 < nt) {
            int k0n = k0 + 32;
            rk = *(const uint4*)(Kg + (size_t)(k0n + krow) * 3072 + d8);
            rv = *(const uint4*)(Vg + k0n + tc);
        }

        if (k0 > qgmin + 15) continue;       // fully-masked tile for this wave

        // swapped QK^T: A = K-frag, B = Q-frag -> D[k][q], q = l15
        facc s[2];
#pragma unroll
        for (int nb = 0; nb < 2; ++nb) {
#pragma unroll
            for (int r = 0; r < 4; ++r) s[nb][r] = 0.f;
#pragma unroll
            for (int kc = 0; kc < 4; ++kc) {
                bfrag kf = *(const bfrag*)&Ks[cur][nb * 16 + l15][kc * 32 + quad * 8];
                s[nb] = __builtin_amdgcn_mfma_f32_16x16x32_bf16(kf, qf[kc], s[nb], 0, 0, 0);
            }
        }

        bool fullT = (k0 + 31) <= qgmin;
        float v[2][4];
        if (fullT) {
#pragma unroll
            for (int nb = 0; nb < 2; ++nb)
#pragma unroll
                for (int r = 0; r < 4; ++r) v[nb][r] = s[nb][r] * sc;
        } else {
#pragma unroll
            for (int nb = 0; nb < 2; ++nb)
#pragma unroll
                for (int r = 0; r < 4; ++r) {
                    int kg = k0 + nb * 16 + quad * 4 + r;
                    v[nb][r] = (kg > myq) ? NEG_BIG : s[nb][r] * sc;
                }
        }

        // row max: 7 local fmax + 2-step quad fold
        float mx = fmaxf(fmaxf(fmaxf(v[0][0], v[0][1]), fmaxf(v[0][2], v[0][3])),
                         fmaxf(fmaxf(v[1][0], v[1][1]), fmaxf(v[1][2], v[1][3])));
        mx = fmaxf(mx, __shfl_xor(mx, 16, 64));
        mx = fmaxf(mx, __shfl_xor(mx, 32, 64));

        bool need = (mx > mreg + 8.f);       // T13 defer-max, THR=8
        float mnew = need ? mx : mreg;
        float alpha = need ? __expf(mreg - mnew) : 1.f;

        float p[2][4];
        float psum = 0.f;
#pragma unroll
        for (int nb = 0; nb < 2; ++nb)
#pragma unroll
            for (int r = 0; r < 4; ++r) {
                p[nb][r] = __expf(v[nb][r] - mnew);   // exp(-huge)=0 for masked
                psum += p[nb][r];
            }
        psum += __shfl_xor(psum, 16, 64);
        psum += __shfl_xor(psum, 32, 64);
        lreg = lreg * alpha + psum;
        mreg = mnew;

        // P -> LDS: lane writes 4 contiguous k per nb (8B each)
#pragma unroll
        for (int nb = 0; nb < 2; ++nb) {
            unsigned short pk[4];
#pragma unroll
            for (int r = 0; r < 4; ++r) pk[r] = f2b(p[nb][r]);
            *(uint2*)&Pt[w][l15][nb * 16 + quad * 4] = *(const uint2*)pk;
        }

        if (__any(need)) {                   // fetch per-q alpha, rescale o
#pragma unroll
            for (int r = 0; r < 4; ++r) {
                float al = __shfl(alpha, quad * 4 + r, 16);
#pragma unroll
                for (int nb2 = 0; nb2 < 8; ++nb2) o[nb2][r] *= al;
            }
        }

        asm volatile("s_waitcnt lgkmcnt(0)" ::: "memory");   // wave-local RAW on Pt[w]
        bfrag pf = *(const bfrag*)&Pt[w][l15][quad * 8];
#pragma unroll
        for (int nb2 = 0; nb2 < 8; ++nb2) {
            bfrag vf = *(const bfrag*)&Vt[cur][nb2 * 16 + l15][quad * 8];
            o[nb2] = __builtin_amdgcn_mfma_f32_16x16x32_bf16(pf, vf, o[nb2], 0, 0, 0);
        }
    }

    // final: fetch per-q l via width-16 shfl, divide, store
    float lr[4];
#pragma unroll
    for (int r = 0; r < 4; ++r) lr[r] = __shfl(lreg, quad * 4 + r, 16);
#pragma unroll
    for (int nb2 = 0; nb2 < 8; ++nb2)
#pragma unroll
        for (int r = 0; r < 4; ++r) {
            int qg = qbase + w * 16 + quad * 4 + r;
            att[(size_t)(b * TT + qg) * 2048 + h * 128 + nb2 * 16 + l15] =
                f2b(o[nb2][r] / lr[r]);
        }
}

__global__ __launch_bounds__(512, 4) void k_flash(const unsigned short* __restrict__ QKV,
                                                  const unsigned short* __restrict__ VbT,
                                                  unsigned short* __restrict__ att) {
    __shared__ alignas(16) unsigned short Ks[2][32][136];
    __shared__ alignas(16) unsigned short Vt[2][128][40];
    __shared__ alignas(16) unsigned short Pt[8][16][40];
    int bh = blockIdx.y;
    int b = bh >> 4, h = bh & 15;
    int kvh = h >> 2;
    int i = blockIdx.x;

    flash_pass(i * 128, b, h, kvh, QKV, VbT, att, Ks, Vt, Pt);
    __syncthreads();
    flash_pass((15 - i) * 128, b, h, kvh, QKV, VbT, att, Ks, Vt, Pt);
}

// ---------------------------------------------------------------------------
extern "C" void kernel_launch(void* const* d_in, const int* in_sizes, int n_in,
                              void* d_out, int out_size, void* d_ws, size_t ws_size,
                              hipStream_t stream) {
    const float* x  = (const float*)d_in[0];
    const float* Wq = (const float*)d_in[1];
    const float* Wk = (const float*)d_in[2];
    const float* Wv = (const float*)d_in[3];
    const float* Wo = (const float*)d_in[4];
    const int* pos  = (const int*)d_in[5];

    char* ws = (char*)d_ws;
    unsigned short* xb   = (unsigned short*)(ws + 0);          // 32 MB (8192x2048); reused as att out
    unsigned short* QKV  = (unsigned short*)(ws + 33554432);   // 48 MB (8192x3072)
    unsigned short* VbT  = (unsigned short*)(ws + 83886080);   //  8 MB (512x8192)
    unsigned short* WqT  = (unsigned short*)(ws + 92274688);   //  8 MB (2048x2048)
    unsigned short* WkvT = (unsigned short*)(ws + 100663296);  //  4 MB (1024x2048) -- contiguous with WqT
    unsigned short* WoT  = (unsigned short*)(ws + 104857600);  //  8 MB -> 108 MB total

    // bf16 conversion + weight transposes (WqT|WkvT form one contiguous 3072x2048 Bt)
    k_cvt<<<8192, 256, 0, stream>>>(x, xb, 2097152);
    k_wt<<<dim3(32, 32), 256, 0, stream>>>(Wq, WqT, 2048);
    k_wt<<<dim3(8, 32),  256, 0, stream>>>(Wk, WkvT, 512);
    k_wt<<<dim3(8, 32),  256, 0, stream>>>(Wv, WkvT + (size_t)512 * 2048, 512);
    k_wt<<<dim3(32, 32), 256, 0, stream>>>(Wo, WoT, 2048);

    // fused Q|K|V projection: 2-phase double-buffered
    k_gemm2ph<<<dim3(24, 64), 256, 0, stream>>>(xb, WqT, QKV, 8192, 3072, 2048, 0);

    // RoPE (Q: 16 heads, cols 0..2047; K: 4 heads, cols 2048..2559; stride 3072)
    k_rope<<<32768, 256, 0, stream>>>(QKV, 4, 3072, pos);
    k_rope<<<8192,  256, 0, stream>>>(QKV + 2048, 2, 3072, pos);

    // V transpose for flash B-frag staging
    k_vt<<<dim3(8, 128), 256, 0, stream>>>(QKV, VbT);

    // causal GQA flash attention (swapped-QK softmax) -> xb
    k_flash<<<dim3(8, 64), 512, 0, stream>>>(QKV, VbT, xb);

    // output projection -> fp32 d_out: 2-phase as well
    k_gemm2ph<<<dim3(16, 64), 256, 0, stream>>>(xb, WoT, d_out, 8192, 2048, 2048, 1);
}